// Round 1
// baseline (1485.906 us; speedup 1.0000x reference)
//
#include <hip/hip_runtime.h>
#include <hip/hip_bf16.h>

#define T_TOK 4096
#define DH 1024
#define DI 1408
#define NE 8
#define TOPK 2

#define BM 64
#define BN 64
#define BK 16

// ---------------- router: logits, softmax, top-2, renorm ----------------
__global__ void router_kernel(const float* __restrict__ x, const float* __restrict__ gw,
                              float* __restrict__ logits_out, int* __restrict__ counts,
                              int* __restrict__ tokE, float* __restrict__ tokW) {
    int wave = threadIdx.x >> 6;
    int lane = threadIdx.x & 63;
    int t = blockIdx.x * 4 + wave;
    if (t >= T_TOK) return;
    const float* xr = x + (size_t)t * DH;

    float acc[NE];
#pragma unroll
    for (int e = 0; e < NE; ++e) acc[e] = 0.f;
    for (int d = lane; d < DH; d += 64) {
        float xv = xr[d];
#pragma unroll
        for (int e = 0; e < NE; ++e) acc[e] += xv * gw[e * DH + d];
    }
#pragma unroll
    for (int e = 0; e < NE; ++e) {
#pragma unroll
        for (int off = 32; off > 0; off >>= 1) acc[e] += __shfl_xor(acc[e], off, 64);
    }
    if (lane == 0) {
        float mx = acc[0];
#pragma unroll
        for (int e = 1; e < NE; ++e) mx = fmaxf(mx, acc[e]);
        float p[NE]; float s = 0.f;
#pragma unroll
        for (int e = 0; e < NE; ++e) { p[e] = expf(acc[e] - mx); s += p[e]; }
        float inv = 1.f / s;
#pragma unroll
        for (int e = 0; e < NE; ++e) p[e] *= inv;
        int i0 = 0, i1 = -1; float p0 = -1.f, p1 = -1.f;
#pragma unroll
        for (int e = 0; e < NE; ++e) {
            float v = p[e];
            if (v > p0) { p1 = p0; i1 = i0; p0 = v; i0 = e; }
            else if (v > p1) { p1 = v; i1 = e; }
        }
        float wsum = p0 + p1;
        float w0 = p0 / wsum, w1 = p1 / wsum;
#pragma unroll
        for (int e = 0; e < NE; ++e) logits_out[(size_t)t * NE + e] = acc[e];
        tokE[2 * t]     = i0;  tokE[2 * t + 1] = i1;
        tokW[2 * t]     = w0;  tokW[2 * t + 1] = w1;
        atomicAdd(&counts[i0], 1);
        atomicAdd(&counts[i1], 1);
    }
}

__global__ void prefix_kernel(const int* __restrict__ counts, int* __restrict__ offsets) {
    if (threadIdx.x == 0) {
        int r = 0;
        for (int e = 0; e < NE; ++e) { offsets[e] = r; r += counts[e]; }
    }
}

__global__ void scatter_kernel(const int* __restrict__ tokE, const float* __restrict__ tokW,
                               const int* __restrict__ offsets, int* __restrict__ cursor,
                               int* __restrict__ assignTok, float* __restrict__ assignW) {
    int t = blockIdx.x * blockDim.x + threadIdx.x;
    if (t >= T_TOK) return;
#pragma unroll
    for (int k = 0; k < TOPK; ++k) {
        int e = tokE[2 * t + k];
        int pos = atomicAdd(&cursor[e], 1);
        int a = offsets[e] + pos;
        assignTok[a] = t;
        assignW[a] = tokW[2 * t + k];
    }
}

// ---------------- grouped GEMM A: h = silu(x Wg^T) * (x Wu^T) ----------------
__global__ __launch_bounds__(256) void gemmA_kernel(const float* __restrict__ x,
        const float* __restrict__ gp, const float* __restrict__ up,
        const int* __restrict__ counts, const int* __restrict__ offsets,
        const int* __restrict__ assignTok, float* __restrict__ h) {
    int e = blockIdx.z;
    int cnt = counts[e];
    int r0 = blockIdx.y * BM;
    if (r0 >= cnt) return;
    int n0 = blockIdx.x * BN;
    int off = offsets[e];

    __shared__ float As[BK][BM + 1];
    __shared__ float Bg[BK][BN + 1];
    __shared__ float Bu[BK][BN + 1];

    int tid = threadIdx.x;
    int lrow = tid >> 2;          // 0..63
    int lk4  = (tid & 3) * 4;     // 0,4,8,12

    int arow = r0 + lrow;
    int asrc = arow < cnt ? arow : cnt - 1;
    int tok = assignTok[off + asrc];
    const float* xr  = x + (size_t)tok * DH;
    const float* gpr = gp + ((size_t)e * DI + (n0 + lrow)) * DH;
    const float* upr = up + ((size_t)e * DI + (n0 + lrow)) * DH;

    int tx = tid & 15, ty = tid >> 4;
    float accG[4][4] = {{0.f}}, accU[4][4] = {{0.f}};

    for (int k0 = 0; k0 < DH; k0 += BK) {
        float4 av = *(const float4*)(xr  + k0 + lk4);
        float4 gv = *(const float4*)(gpr + k0 + lk4);
        float4 uv = *(const float4*)(upr + k0 + lk4);
        As[lk4 + 0][lrow] = av.x; As[lk4 + 1][lrow] = av.y; As[lk4 + 2][lrow] = av.z; As[lk4 + 3][lrow] = av.w;
        Bg[lk4 + 0][lrow] = gv.x; Bg[lk4 + 1][lrow] = gv.y; Bg[lk4 + 2][lrow] = gv.z; Bg[lk4 + 3][lrow] = gv.w;
        Bu[lk4 + 0][lrow] = uv.x; Bu[lk4 + 1][lrow] = uv.y; Bu[lk4 + 2][lrow] = uv.z; Bu[lk4 + 3][lrow] = uv.w;
        __syncthreads();
#pragma unroll
        for (int k = 0; k < BK; ++k) {
            float a[4], g[4], u[4];
#pragma unroll
            for (int i = 0; i < 4; ++i) a[i] = As[k][ty * 4 + i];
#pragma unroll
            for (int j = 0; j < 4; ++j) { g[j] = Bg[k][tx * 4 + j]; u[j] = Bu[k][tx * 4 + j]; }
#pragma unroll
            for (int i = 0; i < 4; ++i)
#pragma unroll
                for (int j = 0; j < 4; ++j) {
                    accG[i][j] += a[i] * g[j];
                    accU[i][j] += a[i] * u[j];
                }
        }
        __syncthreads();
    }
#pragma unroll
    for (int i = 0; i < 4; ++i) {
        int r = r0 + ty * 4 + i;
        if (r >= cnt) continue;
        float* hr = h + (size_t)(off + r) * DI + n0;
#pragma unroll
        for (int j = 0; j < 4; ++j) {
            float g = accG[i][j], u = accU[i][j];
            float val = (g / (1.f + expf(-g))) * u;
            hr[tx * 4 + j] = val;
        }
    }
}

// ---------------- grouped GEMM B: out += w * (h Wd^T) ----------------
__global__ __launch_bounds__(256) void gemmB_kernel(const float* __restrict__ h,
        const float* __restrict__ dp,
        const int* __restrict__ counts, const int* __restrict__ offsets,
        const int* __restrict__ assignTok, const float* __restrict__ assignW,
        float* __restrict__ out) {
    int e = blockIdx.z;
    int cnt = counts[e];
    int r0 = blockIdx.y * BM;
    if (r0 >= cnt) return;
    int n0 = blockIdx.x * BN;
    int off = offsets[e];

    __shared__ float As[BK][BM + 1];
    __shared__ float Bs[BK][BN + 1];

    int tid = threadIdx.x;
    int lrow = tid >> 2;
    int lk4  = (tid & 3) * 4;

    int arow = r0 + lrow;
    int asrc = arow < cnt ? arow : cnt - 1;
    const float* hr  = h + (size_t)(off + asrc) * DI;
    const float* dpr = dp + ((size_t)e * DH + (n0 + lrow)) * DI;

    int tx = tid & 15, ty = tid >> 4;
    float acc[4][4] = {{0.f}};

    for (int k0 = 0; k0 < DI; k0 += BK) {
        float4 av = *(const float4*)(hr  + k0 + lk4);
        float4 bv = *(const float4*)(dpr + k0 + lk4);
        As[lk4 + 0][lrow] = av.x; As[lk4 + 1][lrow] = av.y; As[lk4 + 2][lrow] = av.z; As[lk4 + 3][lrow] = av.w;
        Bs[lk4 + 0][lrow] = bv.x; Bs[lk4 + 1][lrow] = bv.y; Bs[lk4 + 2][lrow] = bv.z; Bs[lk4 + 3][lrow] = bv.w;
        __syncthreads();
#pragma unroll
        for (int k = 0; k < BK; ++k) {
            float a[4], b[4];
#pragma unroll
            for (int i = 0; i < 4; ++i) a[i] = As[k][ty * 4 + i];
#pragma unroll
            for (int j = 0; j < 4; ++j) b[j] = Bs[k][tx * 4 + j];
#pragma unroll
            for (int i = 0; i < 4; ++i)
#pragma unroll
                for (int j = 0; j < 4; ++j) acc[i][j] += a[i] * b[j];
        }
        __syncthreads();
    }
#pragma unroll
    for (int i = 0; i < 4; ++i) {
        int r = r0 + ty * 4 + i;
        if (r >= cnt) continue;
        int tok = assignTok[off + r];
        float w = assignW[off + r];
        float* orow = out + (size_t)tok * DH + n0;
#pragma unroll
        for (int j = 0; j < 4; ++j) atomicAdd(&orow[tx * 4 + j], w * acc[i][j]);
    }
}

extern "C" void kernel_launch(void* const* d_in, const int* in_sizes, int n_in,
                              void* d_out, int out_size, void* d_ws, size_t ws_size,
                              hipStream_t stream) {
    const float* x  = (const float*)d_in[0];
    const float* gw = (const float*)d_in[1];
    const float* gp = (const float*)d_in[2];
    const float* up = (const float*)d_in[3];
    const float* dp = (const float*)d_in[4];
    float* out = (float*)d_out;
    float* logits = out + (size_t)T_TOK * DH;

    char* ws = (char*)d_ws;
    int*   counts    = (int*)(ws + 0);
    int*   cursor    = (int*)(ws + 64);
    int*   offsets   = (int*)(ws + 128);
    int*   tokE      = (int*)(ws + 256);
    float* tokW      = (float*)(ws + 256 + 32768);
    int*   assignTok = (int*)(ws + 256 + 65536);
    float* assignW   = (float*)(ws + 256 + 98304);
    float* h         = (float*)(ws + 131328);   // 8192*1408 floats = 46.1 MB

    hipMemsetAsync(ws, 0, 256, stream);
    hipMemsetAsync(d_out, 0, (size_t)T_TOK * DH * sizeof(float), stream);

    router_kernel<<<T_TOK / 4, 256, 0, stream>>>(x, gw, logits, counts, tokE, tokW);
    prefix_kernel<<<1, 64, 0, stream>>>(counts, offsets);
    scatter_kernel<<<T_TOK / 256, 256, 0, stream>>>(tokE, tokW, offsets, cursor, assignTok, assignW);
    gemmA_kernel<<<dim3(DI / BN, T_TOK / BM, NE), 256, 0, stream>>>(x, gp, up, counts, offsets, assignTok, h);
    gemmB_kernel<<<dim3(DH / BN, T_TOK / BM, NE), 256, 0, stream>>>(h, dp, counts, offsets, assignTok, assignW, out);
}

// Round 2
// 370.212 us; speedup vs baseline: 4.0137x; 4.0137x over previous
//
#include <hip/hip_runtime.h>
#include <hip/hip_bf16.h>
#include <stdint.h>

#define T_TOK 4096
#define DH 1024
#define DI 1408
#define NE 8
#define TOPK 2
#define PADROWS 9216   // 8192 assignments + up to 8*127 pad, rounded

typedef short s16x8 __attribute__((ext_vector_type(8)));
typedef float f32x4 __attribute__((ext_vector_type(4)));

__device__ inline unsigned short f2bf(float f) {
    __hip_bfloat16 h = __float2bfloat16(f);
    return *(unsigned short*)&h;
}

// ---------------- router: logits, softmax, top-2, renorm (fp32 exact) ----------------
__global__ void router_kernel(const float* __restrict__ x, const float* __restrict__ gw,
                              float* __restrict__ logits_out, int* __restrict__ counts,
                              int* __restrict__ tokE, float* __restrict__ tokW) {
    int wave = threadIdx.x >> 6;
    int lane = threadIdx.x & 63;
    int t = blockIdx.x * 4 + wave;
    if (t >= T_TOK) return;
    const float* xr = x + (size_t)t * DH;

    float acc[NE];
#pragma unroll
    for (int e = 0; e < NE; ++e) acc[e] = 0.f;
    for (int d = lane; d < DH; d += 64) {
        float xv = xr[d];
#pragma unroll
        for (int e = 0; e < NE; ++e) acc[e] += xv * gw[e * DH + d];
    }
#pragma unroll
    for (int e = 0; e < NE; ++e) {
#pragma unroll
        for (int off = 32; off > 0; off >>= 1) acc[e] += __shfl_xor(acc[e], off, 64);
    }
    if (lane == 0) {
        float mx = acc[0];
#pragma unroll
        for (int e = 1; e < NE; ++e) mx = fmaxf(mx, acc[e]);
        float p[NE]; float s = 0.f;
#pragma unroll
        for (int e = 0; e < NE; ++e) { p[e] = expf(acc[e] - mx); s += p[e]; }
        float inv = 1.f / s;
#pragma unroll
        for (int e = 0; e < NE; ++e) p[e] *= inv;
        int i0 = 0, i1 = -1; float p0 = -1.f, p1 = -1.f;
#pragma unroll
        for (int e = 0; e < NE; ++e) {
            float v = p[e];
            if (v > p0) { p1 = p0; i1 = i0; p0 = v; i0 = e; }
            else if (v > p1) { p1 = v; i1 = e; }
        }
        float wsum = p0 + p1;
        float w0 = p0 / wsum, w1 = p1 / wsum;
#pragma unroll
        for (int e = 0; e < NE; ++e) logits_out[(size_t)t * NE + e] = acc[e];
        tokE[2 * t]     = i0;  tokE[2 * t + 1] = i1;
        tokW[2 * t]     = w0;  tokW[2 * t + 1] = w1;
        atomicAdd(&counts[i0], 1);
        atomicAdd(&counts[i1], 1);
    }
}

// padOff[e] = start of expert e's 128-padded assignment region; padOff[NE] = total
__global__ void prefix_kernel(const int* __restrict__ counts, int* __restrict__ padOff) {
    if (threadIdx.x == 0) {
        int r = 0;
        for (int e = 0; e < NE; ++e) { padOff[e] = r; r += ((counts[e] + 127) >> 7) << 7; }
        padOff[NE] = r;
    }
}

__global__ void scatter_kernel(const int* __restrict__ tokE, const float* __restrict__ tokW,
                               const int* __restrict__ padOff, int* __restrict__ cursor,
                               int* __restrict__ assignTok, float* __restrict__ assignW) {
    int t = blockIdx.x * blockDim.x + threadIdx.x;
    if (t >= T_TOK) return;
#pragma unroll
    for (int k = 0; k < TOPK; ++k) {
        int e = tokE[2 * t + k];
        int pos = atomicAdd(&cursor[e], 1);
        int a = padOff[e] + pos;
        assignTok[a] = t;
        assignW[a] = tokW[2 * t + k];
    }
}

// gather x rows into assignment order, fp32 -> bf16; zero-fill padded rows
__global__ void gather_kernel(const float* __restrict__ x, const int* __restrict__ padOff,
                              const int* __restrict__ counts, const int* __restrict__ assignTok,
                              unsigned short* __restrict__ xg) {
    int pr = blockIdx.x;
    int e = -1, base = 0;
#pragma unroll
    for (int i = 0; i < NE; ++i)
        if (pr >= padOff[i] && pr < padOff[i + 1]) { e = i; base = padOff[i]; }
    int tid = threadIdx.x;
    unsigned short* dst = xg + (size_t)pr * DH + tid * 4;
    if (e >= 0 && (pr - base) < counts[e]) {
        int tok = assignTok[pr];
        float4 v = *(const float4*)(x + (size_t)tok * DH + tid * 4);
        uint2 o;
        o.x = (unsigned)f2bf(v.x) | ((unsigned)f2bf(v.y) << 16);
        o.y = (unsigned)f2bf(v.z) | ((unsigned)f2bf(v.w) << 16);
        *(uint2*)dst = o;
    } else {
        *(uint2*)dst = make_uint2(0u, 0u);
    }
}

// ---------------- grouped GEMM A: h = silu(xg Wg^T) * (xg Wu^T), bf16 MFMA ----------------
__global__ __launch_bounds__(512) void gemmA_kernel(
        const unsigned short* __restrict__ xg,
        const float* __restrict__ gp, const float* __restrict__ up,
        const int* __restrict__ padOff,
        unsigned short* __restrict__ h) {
    int pr0 = blockIdx.y * 128;
    int e = -1;
#pragma unroll
    for (int i = 0; i < NE; ++i)
        if (pr0 >= padOff[i] && pr0 < padOff[i + 1]) e = i;
    if (e < 0) return;
    int n0 = blockIdx.x * 128;

    __shared__ unsigned short As[128 * 32];       // linear: required by global_load_lds
    __shared__ unsigned short Bgs[128 * 40];      // padded stride 40 (bank-spread)
    __shared__ unsigned short Bus[128 * 40];

    int tid = threadIdx.x;
    int lane = tid & 63;
    int w = tid >> 6;
    int wm = (w >> 2) * 64;     // wave M offset (0/64)
    int wn = (w & 3) * 32;      // wave N offset (0/32/64/96)

    // A staging: wave w loads 16 rows (1 KB) per K-step via global_load_lds
    const unsigned short* a_src = xg + (size_t)(pr0 + w * 16 + (lane >> 2)) * DH + (lane & 3) * 8;
    unsigned short* a_dst = &As[w * 16 * 32];

    // B staging: thread t covers n = t>>2, kq = (t&3)*8
    int bn = tid >> 2;
    int bk = (tid & 3) * 8;
    const float* g_src = gp + ((size_t)e * DI + (n0 + bn)) * DH + bk;
    const float* u_src = up + ((size_t)e * DI + (n0 + bn)) * DH + bk;
    unsigned short* bg_dst = &Bgs[bn * 40 + bk];
    unsigned short* bu_dst = &Bus[bn * 40 + bk];

    f32x4 accG[4][2], accU[4][2];
#pragma unroll
    for (int i = 0; i < 4; ++i)
#pragma unroll
        for (int j = 0; j < 2; ++j) {
            accG[i][j] = (f32x4){0.f, 0.f, 0.f, 0.f};
            accU[i][j] = (f32x4){0.f, 0.f, 0.f, 0.f};
        }

    for (int k0 = 0; k0 < DH; k0 += 32) {
        __builtin_amdgcn_global_load_lds(
            (const __attribute__((address_space(1))) void*)(a_src + k0),
            (__attribute__((address_space(3))) void*)a_dst, 16, 0, 0);
        float4 g0 = *(const float4*)(g_src + k0);
        float4 g1 = *(const float4*)(g_src + k0 + 4);
        float4 u0 = *(const float4*)(u_src + k0);
        float4 u1 = *(const float4*)(u_src + k0 + 4);
        s16x8 pg, pu;
        pg[0] = (short)f2bf(g0.x); pg[1] = (short)f2bf(g0.y);
        pg[2] = (short)f2bf(g0.z); pg[3] = (short)f2bf(g0.w);
        pg[4] = (short)f2bf(g1.x); pg[5] = (short)f2bf(g1.y);
        pg[6] = (short)f2bf(g1.z); pg[7] = (short)f2bf(g1.w);
        pu[0] = (short)f2bf(u0.x); pu[1] = (short)f2bf(u0.y);
        pu[2] = (short)f2bf(u0.z); pu[3] = (short)f2bf(u0.w);
        pu[4] = (short)f2bf(u1.x); pu[5] = (short)f2bf(u1.y);
        pu[6] = (short)f2bf(u1.z); pu[7] = (short)f2bf(u1.w);
        *(s16x8*)bg_dst = pg;
        *(s16x8*)bu_dst = pu;
        __syncthreads();

        s16x8 af[4], bgf[2], buf_[2];
#pragma unroll
        for (int i = 0; i < 4; ++i)
            af[i] = *(const s16x8*)&As[(wm + 16 * i + (lane & 15)) * 32 + (lane >> 4) * 8];
#pragma unroll
        for (int j = 0; j < 2; ++j) {
            bgf[j]  = *(const s16x8*)&Bgs[(wn + 16 * j + (lane & 15)) * 40 + (lane >> 4) * 8];
            buf_[j] = *(const s16x8*)&Bus[(wn + 16 * j + (lane & 15)) * 40 + (lane >> 4) * 8];
        }
#pragma unroll
        for (int i = 0; i < 4; ++i)
#pragma unroll
            for (int j = 0; j < 2; ++j) {
                accG[i][j] = __builtin_amdgcn_mfma_f32_16x16x32_bf16(af[i], bgf[j], accG[i][j], 0, 0, 0);
                accU[i][j] = __builtin_amdgcn_mfma_f32_16x16x32_bf16(af[i], buf_[j], accU[i][j], 0, 0, 0);
            }
        __syncthreads();
    }

    // epilogue: silu(g)*u -> bf16 h (padded rows get garbage, masked downstream)
#pragma unroll
    for (int i = 0; i < 4; ++i) {
        int rowb = pr0 + wm + 16 * i + ((lane >> 4) << 2);
#pragma unroll
        for (int j = 0; j < 2; ++j) {
            int col = n0 + wn + 16 * j + (lane & 15);
#pragma unroll
            for (int r = 0; r < 4; ++r) {
                float g = accG[i][j][r], u = accU[i][j][r];
                float val = (g / (1.f + __expf(-g))) * u;
                h[(size_t)(rowb + r) * DI + col] = f2bf(val);
            }
        }
    }
}

// ---------------- grouped GEMM B: out += w * (h Wd^T), bf16 MFMA ----------------
__global__ __launch_bounds__(512) void gemmB_kernel(
        const unsigned short* __restrict__ h,
        const float* __restrict__ dp,
        const int* __restrict__ padOff, const int* __restrict__ counts,
        const int* __restrict__ assignTok, const float* __restrict__ assignW,
        float* __restrict__ out) {
    int pr0 = blockIdx.y * 128;
    int e = -1, base = 0;
#pragma unroll
    for (int i = 0; i < NE; ++i)
        if (pr0 >= padOff[i] && pr0 < padOff[i + 1]) { e = i; base = padOff[i]; }
    if (e < 0) return;
    int cnt = counts[e];
    int n0 = blockIdx.x * 128;

    __shared__ unsigned short As[128 * 32];
    __shared__ unsigned short Bs[128 * 40];

    int tid = threadIdx.x;
    int lane = tid & 63;
    int w = tid >> 6;
    int wm = (w >> 2) * 64;
    int wn = (w & 3) * 32;

    const unsigned short* a_src = h + (size_t)(pr0 + w * 16 + (lane >> 2)) * DI + (lane & 3) * 8;
    unsigned short* a_dst = &As[w * 16 * 32];

    int bn = tid >> 2;
    int bk = (tid & 3) * 8;
    const float* d_src = dp + ((size_t)e * DH + (n0 + bn)) * DI + bk;
    unsigned short* b_dst = &Bs[bn * 40 + bk];

    f32x4 acc[4][2];
#pragma unroll
    for (int i = 0; i < 4; ++i)
#pragma unroll
        for (int j = 0; j < 2; ++j) acc[i][j] = (f32x4){0.f, 0.f, 0.f, 0.f};

    for (int k0 = 0; k0 < DI; k0 += 32) {
        __builtin_amdgcn_global_load_lds(
            (const __attribute__((address_space(1))) void*)(a_src + k0),
            (__attribute__((address_space(3))) void*)a_dst, 16, 0, 0);
        float4 d0 = *(const float4*)(d_src + k0);
        float4 d1 = *(const float4*)(d_src + k0 + 4);
        s16x8 pd;
        pd[0] = (short)f2bf(d0.x); pd[1] = (short)f2bf(d0.y);
        pd[2] = (short)f2bf(d0.z); pd[3] = (short)f2bf(d0.w);
        pd[4] = (short)f2bf(d1.x); pd[5] = (short)f2bf(d1.y);
        pd[6] = (short)f2bf(d1.z); pd[7] = (short)f2bf(d1.w);
        *(s16x8*)b_dst = pd;
        __syncthreads();

        s16x8 af[4], bf[2];
#pragma unroll
        for (int i = 0; i < 4; ++i)
            af[i] = *(const s16x8*)&As[(wm + 16 * i + (lane & 15)) * 32 + (lane >> 4) * 8];
#pragma unroll
        for (int j = 0; j < 2; ++j)
            bf[j] = *(const s16x8*)&Bs[(wn + 16 * j + (lane & 15)) * 40 + (lane >> 4) * 8];
#pragma unroll
        for (int i = 0; i < 4; ++i)
#pragma unroll
            for (int j = 0; j < 2; ++j)
                acc[i][j] = __builtin_amdgcn_mfma_f32_16x16x32_bf16(af[i], bf[j], acc[i][j], 0, 0, 0);
        __syncthreads();
    }

#pragma unroll
    for (int i = 0; i < 4; ++i) {
        int rowb = pr0 + wm + 16 * i + ((lane >> 4) << 2);
#pragma unroll
        for (int r = 0; r < 4; ++r) {
            int prow = rowb + r;
            if (prow - base < cnt) {
                int tok = assignTok[prow];
                float wgt = assignW[prow];
#pragma unroll
                for (int j = 0; j < 2; ++j) {
                    int col = n0 + wn + 16 * j + (lane & 15);
                    atomicAdd(&out[(size_t)tok * DH + col], wgt * acc[i][j][r]);
                }
            }
        }
    }
}

extern "C" void kernel_launch(void* const* d_in, const int* in_sizes, int n_in,
                              void* d_out, int out_size, void* d_ws, size_t ws_size,
                              hipStream_t stream) {
    const float* x  = (const float*)d_in[0];
    const float* gw = (const float*)d_in[1];
    const float* gp = (const float*)d_in[2];
    const float* up = (const float*)d_in[3];
    const float* dp = (const float*)d_in[4];
    float* out = (float*)d_out;
    float* logits = out + (size_t)T_TOK * DH;

    char* ws = (char*)d_ws;
    int*   counts    = (int*)(ws + 0);
    int*   cursor    = (int*)(ws + 64);
    int*   padOff    = (int*)(ws + 128);                 // 9 ints
    int*   tokE      = (int*)(ws + 1024);                // 32 KB
    float* tokW      = (float*)(ws + 33792);             // 32 KB
    int*   assignTok = (int*)(ws + 66560);               // 36 KB (padded)
    float* assignW   = (float*)(ws + 103424);            // 36 KB
    unsigned short* xg = (unsigned short*)(ws + 140288); // 9216*1024*2 = 18.9 MB
    unsigned short* h  = (unsigned short*)(ws + 140288 + (size_t)PADROWS * DH * 2); // 26 MB

    hipMemsetAsync(ws, 0, 256, stream);
    hipMemsetAsync(d_out, 0, (size_t)T_TOK * DH * sizeof(float), stream);

    router_kernel<<<T_TOK / 4, 256, 0, stream>>>(x, gw, logits, counts, tokE, tokW);
    prefix_kernel<<<1, 64, 0, stream>>>(counts, padOff);
    scatter_kernel<<<T_TOK / 256, 256, 0, stream>>>(tokE, tokW, padOff, cursor, assignTok, assignW);
    gather_kernel<<<PADROWS, 256, 0, stream>>>(x, padOff, counts, assignTok, xg);
    gemmA_kernel<<<dim3(DI / 128, PADROWS / 128), 512, 0, stream>>>(xg, gp, up, padOff, h);
    gemmB_kernel<<<dim3(DH / 128, PADROWS / 128), 512, 0, stream>>>(h, dp, padOff, counts, assignTok, assignW, out);
}

// Round 3
// 325.844 us; speedup vs baseline: 4.5602x; 1.1362x over previous
//
#include <hip/hip_runtime.h>
#include <hip/hip_bf16.h>
#include <stdint.h>

#define T_TOK 4096
#define DH 1024
#define DI 1408
#define NE 8
#define TOPK 2
#define PADROWS 9216   // 8192 assignments + up to 8*127 pad

typedef short s16x8 __attribute__((ext_vector_type(8)));
typedef float f32x4 __attribute__((ext_vector_type(4)));

__device__ inline unsigned f2bf(float f) {
    __hip_bfloat16 h = __float2bfloat16(f);
    return (unsigned)*(unsigned short*)&h;
}

// ---------------- fp32 -> bf16 bulk convert (weights) ----------------
__global__ __launch_bounds__(256) void cvt_kernel(const float* __restrict__ src,
                                                  unsigned short* __restrict__ dst, int n4) {
    int i = blockIdx.x * blockDim.x + threadIdx.x;
    int stride = gridDim.x * blockDim.x;
    for (; i < n4; i += stride) {
        float4 v = ((const float4*)src)[i];
        uint2 o;
        o.x = f2bf(v.x) | (f2bf(v.y) << 16);
        o.y = f2bf(v.z) | (f2bf(v.w) << 16);
        ((uint2*)dst)[i] = o;
    }
}

// ---------------- router: logits, softmax, top-2, renorm; also x->bf16 ----------------
__global__ __launch_bounds__(256) void router_kernel(const float* __restrict__ x,
                              const float* __restrict__ gw,
                              float* __restrict__ logits_out, int* __restrict__ counts,
                              int* __restrict__ tokE, float* __restrict__ tokW,
                              unsigned short* __restrict__ xb) {
    __shared__ float gws[NE * DH];   // 32 KB
    int tid = threadIdx.x;
    for (int i = tid; i < NE * DH / 4; i += 256)
        ((float4*)gws)[i] = ((const float4*)gw)[i];
    __syncthreads();

    int wave = tid >> 6;
    int lane = tid & 63;
    int t = blockIdx.x * 4 + wave;
    const float* xr = x + (size_t)t * DH;

    float acc[NE];
#pragma unroll
    for (int e = 0; e < NE; ++e) acc[e] = 0.f;

    float4 xv[4];
#pragma unroll
    for (int i = 0; i < 4; ++i) {
        xv[i] = ((const float4*)xr)[lane + i * 64];
#pragma unroll
        for (int e = 0; e < NE; ++e) {
            float4 g = ((const float4*)(gws + e * DH))[lane + i * 64];
            acc[e] += xv[i].x * g.x + xv[i].y * g.y + xv[i].z * g.z + xv[i].w * g.w;
        }
    }
    // write bf16 x row (coalesced 8B/lane)
#pragma unroll
    for (int i = 0; i < 4; ++i) {
        uint2 o;
        o.x = f2bf(xv[i].x) | (f2bf(xv[i].y) << 16);
        o.y = f2bf(xv[i].z) | (f2bf(xv[i].w) << 16);
        *(uint2*)(xb + (size_t)t * DH + (lane + i * 64) * 4) = o;
    }
#pragma unroll
    for (int e = 0; e < NE; ++e) {
#pragma unroll
        for (int off = 32; off > 0; off >>= 1) acc[e] += __shfl_xor(acc[e], off, 64);
    }
    if (lane == 0) {
        float mx = acc[0];
#pragma unroll
        for (int e = 1; e < NE; ++e) mx = fmaxf(mx, acc[e]);
        float p[NE]; float s = 0.f;
#pragma unroll
        for (int e = 0; e < NE; ++e) { p[e] = expf(acc[e] - mx); s += p[e]; }
        float inv = 1.f / s;
#pragma unroll
        for (int e = 0; e < NE; ++e) p[e] *= inv;
        int i0 = 0, i1 = -1; float p0 = -1.f, p1 = -1.f;
#pragma unroll
        for (int e = 0; e < NE; ++e) {
            float v = p[e];
            if (v > p0) { p1 = p0; i1 = i0; p0 = v; i0 = e; }
            else if (v > p1) { p1 = v; i1 = e; }
        }
        float wsum = p0 + p1;
#pragma unroll
        for (int e = 0; e < NE; ++e) logits_out[(size_t)t * NE + e] = acc[e];
        tokE[2 * t]     = i0;  tokE[2 * t + 1] = i1;
        tokW[2 * t]     = p0 / wsum;  tokW[2 * t + 1] = p1 / wsum;
        atomicAdd(&counts[i0], 1);
        atomicAdd(&counts[i1], 1);
    }
}

// padOff[e] = start of expert e's 128-padded region; padOff[NE] = total
__global__ void prefix_kernel(const int* __restrict__ counts, int* __restrict__ padOff) {
    if (threadIdx.x == 0) {
        int r = 0;
        for (int e = 0; e < NE; ++e) { padOff[e] = r; r += ((counts[e] + 127) >> 7) << 7; }
        padOff[NE] = r;
    }
}

__global__ void scatter_kernel(const int* __restrict__ tokE, const float* __restrict__ tokW,
                               const int* __restrict__ padOff, int* __restrict__ cursor,
                               int* __restrict__ assignTok, int* __restrict__ tokSlot) {
    int t = blockIdx.x * blockDim.x + threadIdx.x;
    if (t >= T_TOK) return;
#pragma unroll
    for (int k = 0; k < TOPK; ++k) {
        int e = tokE[2 * t + k];
        int pos = atomicAdd(&cursor[e], 1);
        int a = padOff[e] + pos;
        assignTok[a] = t;
        tokSlot[2 * t + k] = a;
    }
}

// ---------------- grouped GEMM A: h = silu(xb[tok] Wg^T) * (xb[tok] Wu^T) ----------------
__global__ __launch_bounds__(512) void gemmA_kernel(
        const unsigned short* __restrict__ xb,
        const unsigned short* __restrict__ gpb, const unsigned short* __restrict__ upb,
        const int* __restrict__ padOff, const int* __restrict__ assignTok,
        unsigned short* __restrict__ h) {
    int pr0 = blockIdx.y * 128;
    int e = -1;
#pragma unroll
    for (int i = 0; i < NE; ++i)
        if (pr0 >= padOff[i] && pr0 < padOff[i + 1]) e = i;
    if (e < 0) return;
    int n0 = blockIdx.x * 128;

    __shared__ unsigned short As[128 * 32];
    __shared__ unsigned short Bgs[128 * 32];
    __shared__ unsigned short Bus[128 * 32];

    int tid = threadIdx.x;
    int lane = tid & 63;
    int w = tid >> 6;
    int wm = (w >> 2) * 64;     // wave M offset (0/64)
    int wn = (w & 3) * 32;      // wave N offset (0/32/64/96)

    // A staging with fused gather: per-lane global src row via assignTok
    int tok = assignTok[pr0 + w * 16 + (lane >> 2)];   // pad entries are 0 (memset)
    const unsigned short* a_src = xb + (size_t)tok * DH + (lane & 3) * 8;
    unsigned short* a_dst = &As[w * 16 * 32];

    int brow = n0 + w * 16 + (lane >> 2);
    const unsigned short* g_src = gpb + ((size_t)e * DI + brow) * DH + (lane & 3) * 8;
    const unsigned short* u_src = upb + ((size_t)e * DI + brow) * DH + (lane & 3) * 8;
    unsigned short* bg_dst = &Bgs[w * 16 * 32];
    unsigned short* bu_dst = &Bus[w * 16 * 32];

    f32x4 accG[4][2], accU[4][2];
#pragma unroll
    for (int i = 0; i < 4; ++i)
#pragma unroll
        for (int j = 0; j < 2; ++j) {
            accG[i][j] = (f32x4){0.f, 0.f, 0.f, 0.f};
            accU[i][j] = (f32x4){0.f, 0.f, 0.f, 0.f};
        }

    for (int k0 = 0; k0 < DH; k0 += 32) {
        __builtin_amdgcn_global_load_lds(
            (const __attribute__((address_space(1))) void*)(a_src + k0),
            (__attribute__((address_space(3))) void*)a_dst, 16, 0, 0);
        __builtin_amdgcn_global_load_lds(
            (const __attribute__((address_space(1))) void*)(g_src + k0),
            (__attribute__((address_space(3))) void*)bg_dst, 16, 0, 0);
        __builtin_amdgcn_global_load_lds(
            (const __attribute__((address_space(1))) void*)(u_src + k0),
            (__attribute__((address_space(3))) void*)bu_dst, 16, 0, 0);
        __syncthreads();

        s16x8 af[4], bgf[2], buf_[2];
#pragma unroll
        for (int i = 0; i < 4; ++i)
            af[i] = *(const s16x8*)&As[(wm + 16 * i + (lane & 15)) * 32 + (lane >> 4) * 8];
#pragma unroll
        for (int j = 0; j < 2; ++j) {
            bgf[j]  = *(const s16x8*)&Bgs[(wn + 16 * j + (lane & 15)) * 32 + (lane >> 4) * 8];
            buf_[j] = *(const s16x8*)&Bus[(wn + 16 * j + (lane & 15)) * 32 + (lane >> 4) * 8];
        }
#pragma unroll
        for (int i = 0; i < 4; ++i)
#pragma unroll
            for (int j = 0; j < 2; ++j) {
                accG[i][j] = __builtin_amdgcn_mfma_f32_16x16x32_bf16(af[i], bgf[j], accG[i][j], 0, 0, 0);
                accU[i][j] = __builtin_amdgcn_mfma_f32_16x16x32_bf16(af[i], buf_[j], accU[i][j], 0, 0, 0);
            }
        __syncthreads();
    }

#pragma unroll
    for (int i = 0; i < 4; ++i) {
        int rowb = pr0 + wm + 16 * i + ((lane >> 4) << 2);
#pragma unroll
        for (int j = 0; j < 2; ++j) {
            int col = n0 + wn + 16 * j + (lane & 15);
#pragma unroll
            for (int r = 0; r < 4; ++r) {
                float g = accG[i][j][r], u = accU[i][j][r];
                float val = (g / (1.f + __expf(-g))) * u;
                h[(size_t)(rowb + r) * DI + col] = (unsigned short)f2bf(val);
            }
        }
    }
}

// ---------------- grouped GEMM B: outP = h Wd^T (raw, weights applied in combine) ----------------
__global__ __launch_bounds__(512) void gemmB_kernel(
        const unsigned short* __restrict__ h,
        const unsigned short* __restrict__ dpb,
        const int* __restrict__ padOff, const int* __restrict__ counts,
        float* __restrict__ outP) {
    int pr0 = blockIdx.y * 128;
    int e = -1, base = 0;
#pragma unroll
    for (int i = 0; i < NE; ++i)
        if (pr0 >= padOff[i] && pr0 < padOff[i + 1]) { e = i; base = padOff[i]; }
    if (e < 0) return;
    int cnt = counts[e];
    int n0 = blockIdx.x * 128;

    __shared__ unsigned short As[128 * 32];
    __shared__ unsigned short Bs[128 * 32];

    int tid = threadIdx.x;
    int lane = tid & 63;
    int w = tid >> 6;
    int wm = (w >> 2) * 64;
    int wn = (w & 3) * 32;

    const unsigned short* a_src = h + (size_t)(pr0 + w * 16 + (lane >> 2)) * DI + (lane & 3) * 8;
    unsigned short* a_dst = &As[w * 16 * 32];

    int brow = n0 + w * 16 + (lane >> 2);
    const unsigned short* b_src = dpb + ((size_t)e * DH + brow) * DI + (lane & 3) * 8;
    unsigned short* b_dst = &Bs[w * 16 * 32];

    f32x4 acc[4][2];
#pragma unroll
    for (int i = 0; i < 4; ++i)
#pragma unroll
        for (int j = 0; j < 2; ++j) acc[i][j] = (f32x4){0.f, 0.f, 0.f, 0.f};

    for (int k0 = 0; k0 < DI; k0 += 32) {
        __builtin_amdgcn_global_load_lds(
            (const __attribute__((address_space(1))) void*)(a_src + k0),
            (__attribute__((address_space(3))) void*)a_dst, 16, 0, 0);
        __builtin_amdgcn_global_load_lds(
            (const __attribute__((address_space(1))) void*)(b_src + k0),
            (__attribute__((address_space(3))) void*)b_dst, 16, 0, 0);
        __syncthreads();

        s16x8 af[4], bf[2];
#pragma unroll
        for (int i = 0; i < 4; ++i)
            af[i] = *(const s16x8*)&As[(wm + 16 * i + (lane & 15)) * 32 + (lane >> 4) * 8];
#pragma unroll
        for (int j = 0; j < 2; ++j)
            bf[j] = *(const s16x8*)&Bs[(wn + 16 * j + (lane & 15)) * 32 + (lane >> 4) * 8];
#pragma unroll
        for (int i = 0; i < 4; ++i)
#pragma unroll
            for (int j = 0; j < 2; ++j)
                acc[i][j] = __builtin_amdgcn_mfma_f32_16x16x32_bf16(af[i], bf[j], acc[i][j], 0, 0, 0);
        __syncthreads();
    }

#pragma unroll
    for (int i = 0; i < 4; ++i) {
        int rowb = pr0 + wm + 16 * i + ((lane >> 4) << 2);
#pragma unroll
        for (int r = 0; r < 4; ++r) {
            int prow = rowb + r;
            if (prow - base < cnt) {
#pragma unroll
                for (int j = 0; j < 2; ++j) {
                    int col = n0 + wn + 16 * j + (lane & 15);
                    outP[(size_t)prow * DH + col] = acc[i][j][r];
                }
            }
        }
    }
}

// ---------------- combine: out[t] = w0*outP[s0] + w1*outP[s1] ----------------
__global__ __launch_bounds__(256) void combine_kernel(const float* __restrict__ outP,
        const int* __restrict__ tokSlot, const float* __restrict__ tokW,
        float* __restrict__ out) {
    int t = blockIdx.x;
    int c = threadIdx.x * 4;
    int s0 = tokSlot[2 * t], s1 = tokSlot[2 * t + 1];
    float w0 = tokW[2 * t], w1 = tokW[2 * t + 1];
    float4 a = *(const float4*)(outP + (size_t)s0 * DH + c);
    float4 b = *(const float4*)(outP + (size_t)s1 * DH + c);
    float4 o;
    o.x = w0 * a.x + w1 * b.x;
    o.y = w0 * a.y + w1 * b.y;
    o.z = w0 * a.z + w1 * b.z;
    o.w = w0 * a.w + w1 * b.w;
    *(float4*)(out + (size_t)t * DH + c) = o;
}

extern "C" void kernel_launch(void* const* d_in, const int* in_sizes, int n_in,
                              void* d_out, int out_size, void* d_ws, size_t ws_size,
                              hipStream_t stream) {
    const float* x  = (const float*)d_in[0];
    const float* gw = (const float*)d_in[1];
    const float* gp = (const float*)d_in[2];
    const float* up = (const float*)d_in[3];
    const float* dp = (const float*)d_in[4];
    float* out = (float*)d_out;
    float* logits = out + (size_t)T_TOK * DH;

    char* ws = (char*)d_ws;
    int*   counts    = (int*)(ws + 0);
    int*   cursor    = (int*)(ws + 64);
    int*   padOff    = (int*)(ws + 128);
    int*   tokE      = (int*)(ws + 4096);                       // 32 KB
    float* tokW      = (float*)(ws + 36864);                    // 32 KB
    int*   tokSlot   = (int*)(ws + 69632);                      // 32 KB
    int*   assignTok = (int*)(ws + 102400);                     // 36 KB
    unsigned short* xb  = (unsigned short*)(ws + 139264);       // 8.39 MB
    unsigned short* gpb = (unsigned short*)(ws + 8527872);      // 23.07 MB
    unsigned short* upb = (unsigned short*)(ws + 31596544);     // 23.07 MB
    unsigned short* dpb = (unsigned short*)(ws + 54665216);     // 23.07 MB
    unsigned short* h   = (unsigned short*)(ws + 77733888);     // 25.95 MB
    float* outP = (float*)(ws + 8527872);  // 37.7 MB, overlaps gpb/upb (dead after gemmA)

    hipMemsetAsync(ws, 0, 256, stream);
    hipMemsetAsync(ws + 102400, 0, PADROWS * 4, stream);  // assignTok pad -> token 0

    const int NW4 = NE * DI * DH / 4;   // 2883584 float4 per weight tensor
    cvt_kernel<<<2048, 256, 0, stream>>>(gp, gpb, NW4);
    cvt_kernel<<<2048, 256, 0, stream>>>(up, upb, NW4);
    cvt_kernel<<<2048, 256, 0, stream>>>(dp, dpb, NW4);

    router_kernel<<<T_TOK / 4, 256, 0, stream>>>(x, gw, logits, counts, tokE, tokW, xb);
    prefix_kernel<<<1, 64, 0, stream>>>(counts, padOff);
    scatter_kernel<<<T_TOK / 256, 256, 0, stream>>>(tokE, tokW, padOff, cursor, assignTok, tokSlot);

    gemmA_kernel<<<dim3(DI / 128, PADROWS / 128), 512, 0, stream>>>(xb, gpb, upb, padOff, assignTok, h);
    gemmB_kernel<<<dim3(DH / 128, PADROWS / 128), 512, 0, stream>>>(h, dpb, padOff, counts, outP);
    combine_kernel<<<T_TOK, 256, 0, stream>>>(outP, tokSlot, tokW, out);
}

// Round 4
// 224.640 us; speedup vs baseline: 6.6146x; 1.4505x over previous
//
#include <hip/hip_runtime.h>
#include <hip/hip_bf16.h>
#include <stdint.h>

#define T_TOK 4096
#define DH 1024
#define DI 1408
#define NE 8
#define TOPK 2
#define PADROWS 9216   // 8192 assignments + up to 8*127 pad

typedef short s16x8 __attribute__((ext_vector_type(8)));
typedef float f32x4 __attribute__((ext_vector_type(4)));

__device__ inline unsigned f2bf(float f) {
    __hip_bfloat16 h = __float2bfloat16(f);
    return (unsigned)*(unsigned short*)&h;
}

// ---------------- fp32 -> bf16 bulk convert (3 weight tensors, one launch) ----------------
__global__ __launch_bounds__(256) void cvt3_kernel(const float* __restrict__ s0,
        const float* __restrict__ s1, const float* __restrict__ s2,
        unsigned short* __restrict__ t0, unsigned short* __restrict__ t1,
        unsigned short* __restrict__ t2, int n4) {
    const float* src = blockIdx.y == 0 ? s0 : (blockIdx.y == 1 ? s1 : s2);
    unsigned short* dst = blockIdx.y == 0 ? t0 : (blockIdx.y == 1 ? t1 : t2);
    int i = blockIdx.x * blockDim.x + threadIdx.x;
    int stride = gridDim.x * blockDim.x;
    for (; i < n4; i += stride) {
        float4 v = ((const float4*)src)[i];
        uint2 o;
        o.x = f2bf(v.x) | (f2bf(v.y) << 16);
        o.y = f2bf(v.z) | (f2bf(v.w) << 16);
        ((uint2*)dst)[i] = o;
    }
}

// ---------------- router: logits, softmax, top-2, renorm; x->bf16. NO atomics ----------------
__global__ __launch_bounds__(256) void router_kernel(const float* __restrict__ x,
                              const float* __restrict__ gw,
                              float* __restrict__ logits_out,
                              int* __restrict__ tokE, float* __restrict__ tokW,
                              unsigned short* __restrict__ xb) {
    int wave = threadIdx.x >> 6;
    int lane = threadIdx.x & 63;
    int t = blockIdx.x * 4 + wave;
    const float4* xr = (const float4*)(x + (size_t)t * DH);

    float acc[NE];
#pragma unroll
    for (int e = 0; e < NE; ++e) acc[e] = 0.f;

#pragma unroll
    for (int i = 0; i < 4; ++i) {
        float4 xv = xr[lane + i * 64];
#pragma unroll
        for (int e = 0; e < NE; ++e) {
            float4 g = ((const float4*)(gw + (size_t)e * DH))[lane + i * 64];
            acc[e] += xv.x * g.x + xv.y * g.y + xv.z * g.z + xv.w * g.w;
        }
        uint2 o;
        o.x = f2bf(xv.x) | (f2bf(xv.y) << 16);
        o.y = f2bf(xv.z) | (f2bf(xv.w) << 16);
        *(uint2*)(xb + (size_t)t * DH + (lane + i * 64) * 4) = o;
    }
#pragma unroll
    for (int e = 0; e < NE; ++e) {
#pragma unroll
        for (int off = 32; off > 0; off >>= 1) acc[e] += __shfl_xor(acc[e], off, 64);
    }
    if (lane == 0) {
        float mx = acc[0];
#pragma unroll
        for (int e = 1; e < NE; ++e) mx = fmaxf(mx, acc[e]);
        float p[NE]; float s = 0.f;
#pragma unroll
        for (int e = 0; e < NE; ++e) { p[e] = expf(acc[e] - mx); s += p[e]; }
        float inv = 1.f / s;
#pragma unroll
        for (int e = 0; e < NE; ++e) p[e] *= inv;
        int i0 = 0, i1 = -1; float p0 = -1.f, p1 = -1.f;
#pragma unroll
        for (int e = 0; e < NE; ++e) {
            float v = p[e];
            if (v > p0) { p1 = p0; i1 = i0; p0 = v; i0 = e; }
            else if (v > p1) { p1 = v; i1 = e; }
        }
        float wsum = p0 + p1;
#pragma unroll
        for (int e = 0; e < NE; ++e) logits_out[(size_t)t * NE + e] = acc[e];
        tokE[2 * t]     = i0;  tokE[2 * t + 1] = i1;
        tokW[2 * t]     = p0 / wsum;  tokW[2 * t + 1] = p1 / wsum;
    }
}

// ---------------- histogram + prefix: single block, ballot popcounts ----------------
__global__ __launch_bounds__(256) void hist_kernel(const int* __restrict__ tokE,
        int* __restrict__ counts, int* __restrict__ padOff) {
    __shared__ int wc[4][NE];
    int tid = threadIdx.x;
    int wave = tid >> 6, lane = tid & 63;
    int cnt[NE];
#pragma unroll
    for (int e = 0; e < NE; ++e) cnt[e] = 0;
    for (int i = tid; i < T_TOK * TOPK; i += 256) {
        int v = tokE[i];
#pragma unroll
        for (int e = 0; e < NE; ++e)
            cnt[e] += (int)__popcll(__ballot(v == e));
    }
    if (lane == 0) {
#pragma unroll
        for (int e = 0; e < NE; ++e) wc[wave][e] = cnt[e];
    }
    __syncthreads();
    if (tid == 0) {
        int r = 0;
        for (int e = 0; e < NE; ++e) {
            int c = wc[0][e] + wc[1][e] + wc[2][e] + wc[3][e];
            counts[e] = c;
            padOff[e] = r;
            r += ((c + 127) >> 7) << 7;
        }
        padOff[NE] = r;
    }
}

// ---------------- scatter: wave-aggregated cursor atomics ----------------
__global__ __launch_bounds__(256) void scatter_kernel(const int* __restrict__ tokE,
                               const int* __restrict__ padOff, int* __restrict__ cursor,
                               int* __restrict__ assignTok, int* __restrict__ tokSlot) {
    int t = blockIdx.x * blockDim.x + threadIdx.x;
    int lane = threadIdx.x & 63;
    unsigned long long lmask = (1ull << lane) - 1ull;
#pragma unroll
    for (int k = 0; k < TOPK; ++k) {
        int e = tokE[2 * t + k];
#pragma unroll
        for (int ex = 0; ex < NE; ++ex) {
            unsigned long long m = __ballot(e == ex);
            if (e == ex) {
                int rank = (int)__popcll(m & lmask);
                int leader = __ffsll((long long)m) - 1;
                int b = 0;
                if (rank == 0) b = atomicAdd(&cursor[ex], (int)__popcll(m));
                b = __shfl(b, leader, 64);
                int slot = padOff[ex] + b + rank;
                assignTok[slot] = t;
                tokSlot[2 * t + k] = slot;
            }
        }
    }
}

// ---------------- grouped GEMM A: h = silu(xb[tok] Wg^T) * (xb[tok] Wu^T) ----------------
__global__ __launch_bounds__(512) void gemmA_kernel(
        const unsigned short* __restrict__ xb,
        const unsigned short* __restrict__ gpb, const unsigned short* __restrict__ upb,
        const int* __restrict__ padOff, const int* __restrict__ assignTok,
        unsigned short* __restrict__ h) {
    int pr0 = blockIdx.y * 128;
    int e = -1;
#pragma unroll
    for (int i = 0; i < NE; ++i)
        if (pr0 >= padOff[i] && pr0 < padOff[i + 1]) e = i;
    if (e < 0) return;
    int n0 = blockIdx.x * 128;

    __shared__ unsigned short As[128 * 32];
    __shared__ unsigned short Bgs[128 * 32];
    __shared__ unsigned short Bus[128 * 32];

    int tid = threadIdx.x;
    int lane = tid & 63;
    int w = tid >> 6;
    int wm = (w >> 2) * 64;
    int wn = (w & 3) * 32;

    int tok = assignTok[pr0 + w * 16 + (lane >> 2)];
    const unsigned short* a_src = xb + (size_t)tok * DH + (lane & 3) * 8;
    unsigned short* a_dst = &As[w * 16 * 32];

    int brow = n0 + w * 16 + (lane >> 2);
    const unsigned short* g_src = gpb + ((size_t)e * DI + brow) * DH + (lane & 3) * 8;
    const unsigned short* u_src = upb + ((size_t)e * DI + brow) * DH + (lane & 3) * 8;
    unsigned short* bg_dst = &Bgs[w * 16 * 32];
    unsigned short* bu_dst = &Bus[w * 16 * 32];

    f32x4 accG[4][2], accU[4][2];
#pragma unroll
    for (int i = 0; i < 4; ++i)
#pragma unroll
        for (int j = 0; j < 2; ++j) {
            accG[i][j] = (f32x4){0.f, 0.f, 0.f, 0.f};
            accU[i][j] = (f32x4){0.f, 0.f, 0.f, 0.f};
        }

    for (int k0 = 0; k0 < DH; k0 += 32) {
        __builtin_amdgcn_global_load_lds(
            (const __attribute__((address_space(1))) void*)(a_src + k0),
            (__attribute__((address_space(3))) void*)a_dst, 16, 0, 0);
        __builtin_amdgcn_global_load_lds(
            (const __attribute__((address_space(1))) void*)(g_src + k0),
            (__attribute__((address_space(3))) void*)bg_dst, 16, 0, 0);
        __builtin_amdgcn_global_load_lds(
            (const __attribute__((address_space(1))) void*)(u_src + k0),
            (__attribute__((address_space(3))) void*)bu_dst, 16, 0, 0);
        __syncthreads();

        s16x8 af[4], bgf[2], buf_[2];
#pragma unroll
        for (int i = 0; i < 4; ++i)
            af[i] = *(const s16x8*)&As[(wm + 16 * i + (lane & 15)) * 32 + (lane >> 4) * 8];
#pragma unroll
        for (int j = 0; j < 2; ++j) {
            bgf[j]  = *(const s16x8*)&Bgs[(wn + 16 * j + (lane & 15)) * 32 + (lane >> 4) * 8];
            buf_[j] = *(const s16x8*)&Bus[(wn + 16 * j + (lane & 15)) * 32 + (lane >> 4) * 8];
        }
#pragma unroll
        for (int i = 0; i < 4; ++i)
#pragma unroll
            for (int j = 0; j < 2; ++j) {
                accG[i][j] = __builtin_amdgcn_mfma_f32_16x16x32_bf16(af[i], bgf[j], accG[i][j], 0, 0, 0);
                accU[i][j] = __builtin_amdgcn_mfma_f32_16x16x32_bf16(af[i], buf_[j], accU[i][j], 0, 0, 0);
            }
        __syncthreads();
    }

#pragma unroll
    for (int i = 0; i < 4; ++i) {
        int rowb = pr0 + wm + 16 * i + ((lane >> 4) << 2);
#pragma unroll
        for (int j = 0; j < 2; ++j) {
            int col = n0 + wn + 16 * j + (lane & 15);
#pragma unroll
            for (int r = 0; r < 4; ++r) {
                float g = accG[i][j][r], u = accU[i][j][r];
                float val = (g / (1.f + __expf(-g))) * u;
                h[(size_t)(rowb + r) * DI + col] = (unsigned short)f2bf(val);
            }
        }
    }
}

// ---------------- grouped GEMM B: outP = h Wd^T ----------------
__global__ __launch_bounds__(512) void gemmB_kernel(
        const unsigned short* __restrict__ h,
        const unsigned short* __restrict__ dpb,
        const int* __restrict__ padOff, const int* __restrict__ counts,
        float* __restrict__ outP) {
    int pr0 = blockIdx.y * 128;
    int e = -1, base = 0;
#pragma unroll
    for (int i = 0; i < NE; ++i)
        if (pr0 >= padOff[i] && pr0 < padOff[i + 1]) { e = i; base = padOff[i]; }
    if (e < 0) return;
    int cnt = counts[e];
    int n0 = blockIdx.x * 128;

    __shared__ unsigned short As[128 * 32];
    __shared__ unsigned short Bs[128 * 32];

    int tid = threadIdx.x;
    int lane = tid & 63;
    int w = tid >> 6;
    int wm = (w >> 2) * 64;
    int wn = (w & 3) * 32;

    const unsigned short* a_src = h + (size_t)(pr0 + w * 16 + (lane >> 2)) * DI + (lane & 3) * 8;
    unsigned short* a_dst = &As[w * 16 * 32];

    int brow = n0 + w * 16 + (lane >> 2);
    const unsigned short* b_src = dpb + ((size_t)e * DH + brow) * DI + (lane & 3) * 8;
    unsigned short* b_dst = &Bs[w * 16 * 32];

    f32x4 acc[4][2];
#pragma unroll
    for (int i = 0; i < 4; ++i)
#pragma unroll
        for (int j = 0; j < 2; ++j) acc[i][j] = (f32x4){0.f, 0.f, 0.f, 0.f};

    for (int k0 = 0; k0 < DI; k0 += 32) {
        __builtin_amdgcn_global_load_lds(
            (const __attribute__((address_space(1))) void*)(a_src + k0),
            (__attribute__((address_space(3))) void*)a_dst, 16, 0, 0);
        __builtin_amdgcn_global_load_lds(
            (const __attribute__((address_space(1))) void*)(b_src + k0),
            (__attribute__((address_space(3))) void*)b_dst, 16, 0, 0);
        __syncthreads();

        s16x8 af[4], bf[2];
#pragma unroll
        for (int i = 0; i < 4; ++i)
            af[i] = *(const s16x8*)&As[(wm + 16 * i + (lane & 15)) * 32 + (lane >> 4) * 8];
#pragma unroll
        for (int j = 0; j < 2; ++j)
            bf[j] = *(const s16x8*)&Bs[(wn + 16 * j + (lane & 15)) * 32 + (lane >> 4) * 8];
#pragma unroll
        for (int i = 0; i < 4; ++i)
#pragma unroll
            for (int j = 0; j < 2; ++j)
                acc[i][j] = __builtin_amdgcn_mfma_f32_16x16x32_bf16(af[i], bf[j], acc[i][j], 0, 0, 0);
        __syncthreads();
    }

#pragma unroll
    for (int i = 0; i < 4; ++i) {
        int rowb = pr0 + wm + 16 * i + ((lane >> 4) << 2);
#pragma unroll
        for (int r = 0; r < 4; ++r) {
            int prow = rowb + r;
            if (prow - base < cnt) {
#pragma unroll
                for (int j = 0; j < 2; ++j) {
                    int col = n0 + wn + 16 * j + (lane & 15);
                    outP[(size_t)prow * DH + col] = acc[i][j][r];
                }
            }
        }
    }
}

// ---------------- combine: out[t] = w0*outP[s0] + w1*outP[s1] ----------------
__global__ __launch_bounds__(256) void combine_kernel(const float* __restrict__ outP,
        const int* __restrict__ tokSlot, const float* __restrict__ tokW,
        float* __restrict__ out) {
    int t = blockIdx.x;
    int c = threadIdx.x * 4;
    int s0 = tokSlot[2 * t], s1 = tokSlot[2 * t + 1];
    float w0 = tokW[2 * t], w1 = tokW[2 * t + 1];
    float4 a = *(const float4*)(outP + (size_t)s0 * DH + c);
    float4 b = *(const float4*)(outP + (size_t)s1 * DH + c);
    float4 o;
    o.x = w0 * a.x + w1 * b.x;
    o.y = w0 * a.y + w1 * b.y;
    o.z = w0 * a.z + w1 * b.z;
    o.w = w0 * a.w + w1 * b.w;
    *(float4*)(out + (size_t)t * DH + c) = o;
}

extern "C" void kernel_launch(void* const* d_in, const int* in_sizes, int n_in,
                              void* d_out, int out_size, void* d_ws, size_t ws_size,
                              hipStream_t stream) {
    const float* x  = (const float*)d_in[0];
    const float* gw = (const float*)d_in[1];
    const float* gp = (const float*)d_in[2];
    const float* up = (const float*)d_in[3];
    const float* dp = (const float*)d_in[4];
    float* out = (float*)d_out;
    float* logits = out + (size_t)T_TOK * DH;

    char* ws = (char*)d_ws;
    int*   counts    = (int*)(ws + 0);
    int*   cursor    = (int*)(ws + 64);
    int*   padOff    = (int*)(ws + 128);
    int*   tokE      = (int*)(ws + 4096);                       // 32 KB
    float* tokW      = (float*)(ws + 36864);                    // 32 KB
    int*   tokSlot   = (int*)(ws + 69632);                      // 32 KB
    int*   assignTok = (int*)(ws + 102400);                     // 36 KB
    unsigned short* xb  = (unsigned short*)(ws + 139264);       // 8.39 MB
    unsigned short* gpb = (unsigned short*)(ws + 8527872);      // 23.07 MB
    unsigned short* upb = (unsigned short*)(ws + 31596544);     // 23.07 MB
    unsigned short* dpb = (unsigned short*)(ws + 54665216);     // 23.07 MB
    unsigned short* h   = (unsigned short*)(ws + 77733888);     // 25.95 MB
    float* outP = (float*)(ws + 8527872);  // 37.7 MB, overlaps gpb/upb (dead after gemmA)

    hipMemsetAsync(ws, 0, 256, stream);
    hipMemsetAsync(ws + 102400, 0, PADROWS * 4, stream);  // assignTok pad -> token 0

    const int NW4 = NE * DI * DH / 4;
    cvt3_kernel<<<dim3(1024, 3), 256, 0, stream>>>(gp, up, dp, gpb, upb, dpb, NW4);

    router_kernel<<<T_TOK / 4, 256, 0, stream>>>(x, gw, logits, tokE, tokW, xb);
    hist_kernel<<<1, 256, 0, stream>>>(tokE, counts, padOff);
    scatter_kernel<<<T_TOK / 256, 256, 0, stream>>>(tokE, padOff, cursor, assignTok, tokSlot);

    gemmA_kernel<<<dim3(DI / 128, PADROWS / 128), 512, 0, stream>>>(xb, gpb, upb, padOff, assignTok, h);
    gemmB_kernel<<<dim3(DH / 128, PADROWS / 128), 512, 0, stream>>>(h, dpb, padOff, counts, outP);
    combine_kernel<<<T_TOK, 256, 0, stream>>>(outP, tokSlot, tokW, out);
}